// Round 6
// baseline (112.815 us; speedup 1.0000x reference)
//
#include <hip/hip_runtime.h>
#include <math.h>

// Chamfer loss, two 16384x3 fp32 clouds. Two plain stream launches.
//
// Pass 1 (compute, ~95% of work): per-(qchunk, DB-slice) block computes
//   partial mins of (||b||^2 - 2 a.b) using inline-asm v_pk_fma_f32
//   (2 DB points per instr; R4 proved __builtin_elementwise_fma stays
//   scalar) + v_min3 => 2 VALU instr per pair, floor ~13.7us.
//   Plain coalesced stores to mins[S][2N] (8.4MB) — no atomics (R4's
//   cross-XCD atomicMin wrote 16.8MB through HBM and serialized).
//   Block 0 also zeroes the ticket counter for pass 2 (kernel-boundary
//   ordering makes it visible; ws is re-poisoned 0xAA before every call).
//
// Pass 2 (finish): 128 blocks combine S slice-mins per query, sqrt,
//   block-reduce, publish agent-scope partial + take a ticket; the LAST
//   block reduces the 128 partials (fixed tree, deterministic) -> out[0].
//   No cooperative launch (R5's hipLaunchCooperativeKernel silently
//   failed), no memset dispatches.

typedef float v2f __attribute__((ext_vector_type(2)));

#define BLOCK  256
#define QPT    8      // queries per thread
#define SLICES 64     // DB slices; pass-1 grid = 16 * 64 = 1024 blocks

__device__ __forceinline__ v2f pk_fma(v2f a, v2f b, v2f c) {
    v2f d;
    asm("v_pk_fma_f32 %0, %1, %2, %3" : "=v"(d) : "v"(a), "v"(b), "v"(c));
    return d;
}

__global__ __launch_bounds__(BLOCK) void chamfer_partial_min(
    const float* __restrict__ state_x, const float* __restrict__ target,
    float* __restrict__ mins, unsigned* __restrict__ counter, int N)
{
    const int tid = threadIdx.x;
    const int twoN = 2 * N;
    const int qchunk = blockIdx.x / SLICES;     // block-uniform
    const int s = blockIdx.x % SLICES;
    const int qbase = qchunk * (BLOCK * QPT);   // 2048-query chunk, 2048 | N

    if (blockIdx.x == 0 && tid == 0) *counter = 0u;   // for pass-2 ticket

    const float* qcloud;
    const float* db;
    int qoff;
    if (qbase < N) { qcloud = target;  db = state_x; qoff = qbase;     }
    else           { qcloud = state_x; db = target;  qoff = qbase - N; }

    // Per-thread queries, -2*coord splatted for pk_fma.
    v2f mx[QPT], my[QPT], mz[QPT];
    float m[QPT];
    #pragma unroll
    for (int q = 0; q < QPT; ++q) {
        const int qidx = qoff + q * BLOCK + tid;
        const float x = -2.0f * qcloud[3 * qidx + 0];
        const float y = -2.0f * qcloud[3 * qidx + 1];
        const float z = -2.0f * qcloud[3 * qidx + 2];
        mx[q] = (v2f){x, x};
        my[q] = (v2f){y, y};
        mz[q] = (v2f){z, z};
        m[q] = 3.0e38f;
    }

    // Whole slice staged once: sliceN = N/SLICES = 256 pts = 128 pairs = 4KB.
    __shared__ float4 tile[2 * (16384 / SLICES / 2)];
    const int sliceN = N / SLICES;
    const int pairs = sliceN / 2;
    const int base0 = s * sliceN;

    for (int p = tid; p < pairs; p += BLOCK) {
        const int g = base0 + 2 * p;
        const float x0 = db[3 * g + 0], y0 = db[3 * g + 1], z0 = db[3 * g + 2];
        const float x1 = db[3 * g + 3], y1 = db[3 * g + 4], z1 = db[3 * g + 5];
        tile[2 * p + 0] = make_float4(x0, x1, y0, y1);
        tile[2 * p + 1] = make_float4(z0, z1,
                                      fmaf(x0, x0, fmaf(y0, y0, z0 * z0)),
                                      fmaf(x1, x1, fmaf(y1, y1, z1 * z1)));
    }
    __syncthreads();

    // Per pair-iteration (2 DB points): 2 broadcast ds_read_b128,
    // QPT*(3 pk_fma + 1 min3) = 32 VALU instr.
    #pragma unroll 4
    for (int p = 0; p < pairs; ++p) {
        const float4 A = tile[2 * p + 0];   // x0 x1 y0 y1
        const float4 B = tile[2 * p + 1];   // z0 z1 w0 w1
        const v2f X = (v2f){A.x, A.y};
        const v2f Y = (v2f){A.z, A.w};
        const v2f Z = (v2f){B.x, B.y};
        const v2f W = (v2f){B.z, B.w};
        #pragma unroll
        for (int q = 0; q < QPT; ++q) {
            v2f d = pk_fma(X, mx[q], W);
            d = pk_fma(Y, my[q], d);
            d = pk_fma(Z, mz[q], d);
            m[q] = fminf(fminf(m[q], d.x), d.y);   // v_min3_f32
        }
    }

    #pragma unroll
    for (int q = 0; q < QPT; ++q)
        mins[(size_t)s * twoN + qbase + q * BLOCK + tid] = m[q];
}

__global__ __launch_bounds__(BLOCK) void chamfer_finish(
    const float* __restrict__ state_x, const float* __restrict__ target,
    const float* __restrict__ mins, float* __restrict__ partials,
    unsigned* __restrict__ counter, float* __restrict__ out, int N)
{
    const int tid = threadIdx.x;
    const int qi = blockIdx.x * BLOCK + tid;
    const int twoN = 2 * N;

    const float* qcloud = (qi < N) ? target : state_x;
    const int qidx = (qi < N) ? qi : qi - N;
    const float ax = qcloud[3 * qidx + 0];
    const float ay = qcloud[3 * qidx + 1];
    const float az = qcloud[3 * qidx + 2];
    const float a2 = fmaf(ax, ax, fmaf(ay, ay, az * az));

    float mm = 3.0e38f;
    #pragma unroll 16
    for (int ss = 0; ss < SLICES; ++ss)
        mm = fminf(mm, mins[(size_t)ss * twoN + qi]);

    float v = sqrtf(fmaxf(a2 + mm, 0.0f));

    for (int off = 32; off > 0; off >>= 1) v += __shfl_down(v, off, 64);
    __shared__ float wsum[4];
    if ((tid & 63) == 0) wsum[tid >> 6] = v;
    __syncthreads();

    __shared__ unsigned is_last;
    if (tid == 0) {
        const float bsum = wsum[0] + wsum[1] + wsum[2] + wsum[3];
        __hip_atomic_store(&partials[blockIdx.x], bsum,
                           __ATOMIC_RELEASE, __HIP_MEMORY_SCOPE_AGENT);
        const unsigned old = __hip_atomic_fetch_add(counter, 1u,
                           __ATOMIC_ACQ_REL, __HIP_MEMORY_SCOPE_AGENT);
        is_last = (old == gridDim.x - 1) ? 1u : 0u;
    }
    __syncthreads();

    if (is_last) {   // exactly one block; deterministic fixed-tree sum
        float p = (tid < (int)gridDim.x)
                ? __hip_atomic_load(&partials[tid],
                                    __ATOMIC_ACQUIRE, __HIP_MEMORY_SCOPE_AGENT)
                : 0.0f;
        for (int off = 32; off > 0; off >>= 1) p += __shfl_down(p, off, 64);
        __shared__ float w2[4];
        if ((tid & 63) == 0) w2[tid >> 6] = p;
        __syncthreads();
        if (tid == 0)
            out[0] = (w2[0] + w2[1] + w2[2] + w2[3]) * 5.0f / (float)N;
    }
}

extern "C" void kernel_launch(void* const* d_in, const int* in_sizes, int n_in,
                              void* d_out, int out_size, void* d_ws, size_t ws_size,
                              hipStream_t stream)
{
    const float* state_x = (const float*)d_in[0];
    const float* target  = (const float*)d_in[1];
    float* out = (float*)d_out;

    const int N = in_sizes[0] / 3;               // 16384
    const int twoN = 2 * N;
    const int nFinishBlocks = twoN / BLOCK;      // 128

    float* mins = (float*)d_ws;                  // SLICES*2N floats = 8.4 MB
    float* partials = mins + (size_t)SLICES * twoN;
    unsigned* counter = (unsigned*)(partials + nFinishBlocks);

    const int qchunks = twoN / (BLOCK * QPT);    // 16
    chamfer_partial_min<<<qchunks * SLICES, BLOCK, 0, stream>>>(
        state_x, target, mins, counter, N);
    chamfer_finish<<<nFinishBlocks, BLOCK, 0, stream>>>(
        state_x, target, mins, partials, counter, out, N);
}